// Round 1
// baseline (745.131 us; speedup 1.0000x reference)
//
#include <hip/hip_runtime.h>
#include <stdint.h>

// SGRSelector: per-row exact top-K indices, sorted by value desc, ties -> lower index.
// B=256, S=131072, K=S/8=16384. Output: int32 [B,K] indices ++ [K] scalar.
// Histogram path in the reference is dead code (result unused) -> skipped.

#define TPB     1024
#define S_LEN   131072
#define K_SEL   (S_LEN / 8)     // 16384
#define WINSZ   8192            // LDS sort window (8192 * 8B = 64 KiB)
#define IDX_MASK 0x1FFFFu       // 17 bits for index
#define EQ_CAP  4096

// 64 KiB shared, phase-aliased:
//   select phases: hist[2048] + eq[4096] + cnt[4]   (~24.6 KiB used)
//   sort phase   : sortBuf[8192] u64                 (64 KiB)
union SMem {
  unsigned long long sortBuf[WINSZ];
  struct {
    unsigned int hist[2048];
    unsigned int eq[EQ_CAP];
    unsigned int cnt[4];   // [0]=candCount, [1]=eqCount, [2]=found bucket
  } s;
};

__device__ __forceinline__ unsigned int ordered_u32(float f) {
  // Monotonic float->uint mapping: larger float => larger uint. (-0.0 < +0.0)
  unsigned int x = __float_as_uint(f);
  unsigned int mask = (unsigned int)((int)x >> 31) | 0x80000000u;
  return x ^ mask;
}

__global__ __launch_bounds__(TPB)
void sgr_topk_kernel(const float* __restrict__ in, int* __restrict__ out,
                     unsigned long long* __restrict__ candAll,
                     int B, long long out_size) {
  const int row = blockIdx.x;
  const int tid = threadIdx.x;
  const float* rowp = in + (size_t)row * S_LEN;
  unsigned long long* cand = candAll + (size_t)row * K_SEL;
  int* orow = out + (size_t)row * K_SEL;

  __shared__ SMem sm;

  // Inclusive suffix sum over sm.s.hist[0..nbins) (Hillis-Steele).
  auto suffix_scan = [&](int nbins) {
    for (int off = 1; off < nbins; off <<= 1) {
      unsigned int v0 = 0, v1 = 0;
      int t2 = tid + TPB;
      if (tid < nbins) v0 = sm.s.hist[tid] + ((tid + off < nbins) ? sm.s.hist[tid + off] : 0u);
      if (t2  < nbins) v1 = sm.s.hist[t2]  + ((t2  + off < nbins) ? sm.s.hist[t2  + off] : 0u);
      __syncthreads();
      if (tid < nbins) sm.s.hist[tid] = v0;
      if (t2  < nbins) sm.s.hist[t2]  = v1;
      __syncthreads();
    }
  };
  // After suffix_scan: find unique b with suffix[b] >= Kneed > suffix[b+1].
  auto find_bucket = [&](unsigned int Kneed, int nbins) -> unsigned int {
    for (int b = tid; b < nbins; b += TPB) {
      unsigned int sb  = sm.s.hist[b];
      unsigned int sb1 = (b + 1 < nbins) ? sm.s.hist[b + 1] : 0u;
      if (sb >= Kneed && sb1 < Kneed) sm.s.cnt[2] = (unsigned int)b;
    }
    __syncthreads();
    return sm.s.cnt[2];
  };
  // One bitonic compare-exchange pass over the LDS window; overall DESCENDING order.
  auto lds_pass = [&](int k, int j, int base) {
    for (int l = tid; l < WINSZ; l += TPB) {
      int p = l ^ j;
      if (p > l) {
        bool asc = (((base + l) & k) != 0);   // flipped -> global descending
        unsigned long long a = sm.sortBuf[l];
        unsigned long long c = sm.sortBuf[p];
        bool sw = asc ? (a > c) : (a < c);
        if (sw) { sm.sortBuf[l] = c; sm.sortBuf[p] = a; }
      }
    }
    __syncthreads();
  };

  // ---------- Level 1: histogram of top 11 bits ----------
  for (int i = tid; i < 2048; i += TPB) sm.s.hist[i] = 0;
  if (tid == 0) { sm.s.cnt[0] = 0; sm.s.cnt[1] = 0; }
  __syncthreads();
  for (int i = tid; i < S_LEN; i += TPB) {
    unsigned int u = ordered_u32(rowp[i]);
    atomicAdd(&sm.s.hist[u >> 21], 1u);
  }
  __syncthreads();
  suffix_scan(2048);
  unsigned int Kneed = K_SEL;
  const unsigned int b1 = find_bucket(Kneed, 2048);
  const unsigned int g1 = (b1 + 1 < 2048) ? sm.s.hist[b1 + 1] : 0u;  // strictly above b1
  Kneed -= g1;
  __syncthreads();

  // ---------- Level 2: mid 11 bits within bucket b1; gather top11 > b1 ----------
  for (int i = tid; i < 2048; i += TPB) sm.s.hist[i] = 0;
  __syncthreads();
  for (int i = tid; i < S_LEN; i += TPB) {
    unsigned int u = ordered_u32(rowp[i]);
    unsigned int top = u >> 21;
    if (top == b1) {
      atomicAdd(&sm.s.hist[(u >> 10) & 2047u], 1u);
    } else if (top > b1) {
      unsigned int pos = atomicAdd(&sm.s.cnt[0], 1u);
      cand[pos] = ((unsigned long long)u << 17) | (unsigned long long)(IDX_MASK - (unsigned int)i);
    }
  }
  __syncthreads();
  suffix_scan(2048);
  const unsigned int b2 = find_bucket(Kneed, 2048);
  const unsigned int g2 = (b2 + 1 < 2048) ? sm.s.hist[b2 + 1] : 0u;
  Kneed -= g2;
  const unsigned int hi22 = (b1 << 11) | b2;
  __syncthreads();

  // ---------- Level 3: low 10 bits within (b1,b2); gather mid > b2 ----------
  for (int i = tid; i < 1024; i += TPB) sm.s.hist[i] = 0;
  __syncthreads();
  for (int i = tid; i < S_LEN; i += TPB) {
    unsigned int u = ordered_u32(rowp[i]);
    if ((u >> 21) == b1) {
      unsigned int mid = (u >> 10) & 2047u;
      if (mid == b2) {
        atomicAdd(&sm.s.hist[u & 1023u], 1u);
      } else if (mid > b2) {
        unsigned int pos = atomicAdd(&sm.s.cnt[0], 1u);
        cand[pos] = ((unsigned long long)u << 17) | (unsigned long long)(IDX_MASK - (unsigned int)i);
      }
    }
  }
  __syncthreads();
  suffix_scan(1024);
  const unsigned int b3 = find_bucket(Kneed, 1024);
  const unsigned int g3 = (b3 + 1 < 1024) ? sm.s.hist[b3 + 1] : 0u;
  const unsigned int needed = Kneed - g3;              // ties to take at u_T (>=1)
  const unsigned int uT = (hi22 << 10) | b3;
  __syncthreads();

  // ---------- Pass 4: gather low > b3 within (b1,b2); collect equals ----------
  for (int i = tid; i < S_LEN; i += TPB) {
    unsigned int u = ordered_u32(rowp[i]);
    if ((u >> 10) == hi22) {
      unsigned int low = u & 1023u;
      if (low > b3) {
        unsigned int pos = atomicAdd(&sm.s.cnt[0], 1u);
        cand[pos] = ((unsigned long long)u << 17) | (unsigned long long)(IDX_MASK - (unsigned int)i);
      } else if (low == b3) {
        unsigned int pos = atomicAdd(&sm.s.cnt[1], 1u);
        if (pos < EQ_CAP) sm.s.eq[pos] = (unsigned int)i;  // u == uT exactly
      }
    }
  }
  __syncthreads();
  const unsigned int candCnt = sm.s.cnt[0];            // == count(u > uT) == K - needed
  unsigned int eqCnt = sm.s.cnt[1];
  if (eqCnt > EQ_CAP) eqCnt = EQ_CAP;                  // astronomically unlikely overflow

  // ---------- Sort equals ascending (small LDS bitonic), emit tail of output ----------
  for (int i = tid; i < EQ_CAP; i += TPB)
    if (i >= (int)eqCnt) sm.s.eq[i] = 0xFFFFFFFFu;
  __syncthreads();
  for (int k = 2; k <= EQ_CAP; k <<= 1) {
    for (int j = k >> 1; j > 0; j >>= 1) {
      for (int l = tid; l < EQ_CAP; l += TPB) {
        int p = l ^ j;
        if (p > l) {
          bool asc = ((l & k) == 0);
          unsigned int a = sm.s.eq[l], c = sm.s.eq[p];
          bool sw = asc ? (a > c) : (a < c);
          if (sw) { sm.s.eq[l] = c; sm.s.eq[p] = a; }
        }
      }
      __syncthreads();
    }
  }
  for (unsigned int j = tid; j < needed; j += TPB)
    orow[candCnt + j] = (int)sm.s.eq[j];
  // zero-pad candidates (pad key 0 < any real key since u > uT >= 0 -> u >= 1)
  for (unsigned int i = candCnt + tid; i < K_SEL; i += TPB) cand[i] = 0ull;
  __syncthreads();

  // ---------- Hybrid bitonic sort of 16384 candidates, descending ----------
  // Phase 1: each 8192 window fully processed for k=2..8192 in LDS.
  for (int w = 0; w < 2; ++w) {
    const int base = w * WINSZ;
    for (int l = tid; l < WINSZ; l += TPB) sm.sortBuf[l] = cand[base + l];
    __syncthreads();
    for (int k = 2; k <= WINSZ; k <<= 1)
      for (int j = k >> 1; j > 0; j >>= 1)
        lds_pass(k, j, base);
    for (int l = tid; l < WINSZ; l += TPB) cand[base + l] = sm.sortBuf[l];
    __syncthreads();
  }
  // Phase 2: k=16384, j=8192 — the one cross-window pass, in global memory.
  for (int l = tid; l < WINSZ; l += TPB) {
    unsigned long long a = cand[l], c = cand[l + WINSZ];
    if (a < c) { cand[l] = c; cand[l + WINSZ] = a; }   // dir = descending
  }
  __syncthreads();
  // Phase 3: k=16384, j=4096..1 per window in LDS; write output directly.
  for (int w = 0; w < 2; ++w) {
    const int base = w * WINSZ;
    for (int l = tid; l < WINSZ; l += TPB) sm.sortBuf[l] = cand[base + l];
    __syncthreads();
    for (int j = WINSZ >> 1; j > 0; j >>= 1)
      lds_pass(16384, j, base);
    for (int l = tid; l < WINSZ; l += TPB) {
      int o = base + l;
      if (o < (int)candCnt)
        orow[o] = (int)(IDX_MASK - (unsigned int)(sm.sortBuf[l] & IDX_MASK));
    }
    __syncthreads();
  }

  // ---------- Scalar second output: K ----------
  if (row == 0 && tid == 0) {
    long long pos = (long long)B * K_SEL;
    if (pos < out_size) out[pos] = K_SEL;
  }
}

extern "C" void kernel_launch(void* const* d_in, const int* in_sizes, int n_in,
                              void* d_out, int out_size, void* d_ws, size_t ws_size,
                              hipStream_t stream) {
  const float* importance = (const float*)d_in[0];
  int B = in_sizes[0] / S_LEN;
  if (B < 1) B = 1;
  // Workspace: B * K * 8 bytes = 32 MiB of candidate keys.
  unsigned long long* cand = (unsigned long long*)d_ws;
  (void)ws_size; (void)n_in;
  sgr_topk_kernel<<<dim3(B), dim3(TPB), 0, stream>>>(
      importance, (int*)d_out, cand, B, (long long)out_size);
}